// Round 3
// baseline (479.508 us; speedup 1.0000x reference)
//
#include <hip/hip_runtime.h>

// ---------------------------------------------------------------------------
// InternalSequenceEmbedder: bidirectional diagonal linear SSM + MLP.
// B=32, T=8192, E=256, D=32, H=32, M=64.
//
// Round 3:
//  kA: A-fragments built directly in registers from e (no LDS staging, no
//      per-subtile barriers; 2 barriers total), B-frags direct from global
//      (32 KB, L2-resident). Scan processes 2 channels/thread via b32 LDS
//      ops (8 sub-chunks of 32). LDS 33 KB -> 4 blocks/CU.
//  kB: carry-fixup decay powers via incremental a^16 recurrence (table from
//      k0) instead of per-element exp2f; cin folded into the power.
//  k0_prep/k3_carry: as before (+ a16 table).
// ---------------------------------------------------------------------------

typedef unsigned short u16;
typedef unsigned int   u32;
typedef __bf16 bf16x8 __attribute__((ext_vector_type(8)));
typedef float  f32x4  __attribute__((ext_vector_type(4)));

constexpr int BB = 32, TT = 8192, NCH = 64;
constexpr int BT = BB * TT;            // 262144 tokens
constexpr int LCH = 256;               // scan chunk length
constexpr int NCHUNK = TT / LCH;       // 32

#define MFMA16(av, bv, cc) __builtin_amdgcn_mfma_f32_16x16x32_bf16((av), (bv), (cc), 0, 0, 0)

__device__ __forceinline__ u16 f2bf(float x) {
    union { float f; u32 u; } v; v.f = x;
    u32 r = (v.u + 0x7FFFu + ((v.u >> 16) & 1u)) >> 16;
    return (u16)r;
}
__device__ __forceinline__ float bf2f(u16 x) {
    union { u32 u; float f; } v; v.u = ((u32)x) << 16;
    return v.f;
}
__device__ __forceinline__ float gelu_tanh(float x) {
    // jax.nn.gelu default (approximate=True)
    float inner = 0.7978845608028654f * fmaf(0.044715f * x, x * x, x);
    float ez = __expf(2.f * inner);
    float t = 1.f - 2.f / (ez + 1.f);        // NaN-free tanh
    return 0.5f * x * (1.f + t);
}

// ---------------------------------------------------------------------------
__global__ void k0_prep(const float* __restrict__ Wpi, const float* __restrict__ bpi,
                        const float* __restrict__ fWin, const float* __restrict__ fbin,
                        const float* __restrict__ floga,
                        const float* __restrict__ bWin, const float* __restrict__ bbin,
                        const float* __restrict__ bloga,
                        const float* __restrict__ fW1, const float* __restrict__ bW1,
                        const float* __restrict__ fW2, const float* __restrict__ bW2,
                        const float* __restrict__ fb2, const float* __restrict__ bb2,
                        const float* __restrict__ fWout, const float* __restrict__ bWout,
                        const float* __restrict__ Wpo, const float* __restrict__ bpo,
                        u16* __restrict__ WuT, float* __restrict__ bu,
                        float* __restrict__ a_arr, float* __restrict__ l2a,
                        float* __restrict__ a16p,
                        u16* __restrict__ W1Tbf, u16* __restrict__ W2poCatT,
                        u16* __restrict__ WoutTbf, u16* __restrict__ WpoCatT,
                        float* __restrict__ bc)
{
    const int blk = blockIdx.x, tid = threadIdx.x;
    if (blk < 64) {                       // WuT row n = (Wpi @ Win) column n
        const float* Win = (blk < 32) ? fWin : bWin;
        const int nn = blk & 31;
        float s = 0.f;
        #pragma unroll
        for (int d = 0; d < 32; ++d) s = fmaf(Wpi[tid * 32 + d], Win[d * 32 + nn], s);
        WuT[blk * 256 + tid] = f2bf(s);
        if (tid == 0) {
            const float* bin = (blk < 32) ? fbin : bbin;
            float sb = bin[nn];
            for (int d = 0; d < 32; ++d) sb = fmaf(bpi[d], Win[d * 32 + nn], sb);
            bu[blk] = sb;
        }
    } else if (blk == 64) {
        if (tid < 64) {                   // decay + log2 + a^16 table
            const float* lg = (tid < 32) ? floga : bloga;
            float a = 1.f / (1.f + __expf(-lg[tid & 31]));
            float l2 = log2f(a);
            a_arr[tid] = a;
            l2a[tid] = l2;
            a16p[tid] = exp2f(16.f * l2);
        } else if (tid < 96) {            // bc = bpo + fb2@WpoF + bb2@WpoB
            int i = tid - 64;
            float s = bpo[i];
            for (int d = 0; d < 32; ++d) s = fmaf(fb2[d], Wpo[d * 32 + i], s);
            for (int d = 0; d < 32; ++d) s = fmaf(bb2[d], Wpo[(32 + d) * 32 + i], s);
            bc[i] = s;
        }
    } else if (blk == 65 || blk == 66) {  // W1T bf16 [dir][64n][32k]
        int dir = blk - 65;
        const float* W1 = dir ? bW1 : fW1;
        for (int x = tid; x < 2048; x += 256) {
            int n = x >> 5, k = x & 31;
            W1Tbf[dir * 2048 + n * 32 + k] = f2bf(W1[k * 64 + n]);
        }
    } else if (blk == 67 || blk == 68) {  // W2@Wpo fold -> [32n][128k], k=dir*64+j
        int dir = blk - 67;
        const float* W2 = dir ? bW2 : fW2;
        const float* Wp = Wpo + dir * 32 * 32;
        for (int x = tid; x < 2048; x += 256) {
            int j = x >> 5, i = x & 31;
            float s = 0.f;
            for (int d = 0; d < 32; ++d) s = fmaf(W2[j * 32 + d], Wp[d * 32 + i], s);
            W2poCatT[i * 128 + dir * 64 + j] = f2bf(s);
        }
    } else if (blk == 69 || blk == 70) {  // WoutT bf16 [dir][32n][32k]
        int dir = blk - 69;
        const float* Wout = dir ? bWout : fWout;
        for (int x = tid; x < 1024; x += 256) {
            int n = x >> 5, k = x & 31;
            WoutTbf[dir * 1024 + n * 32 + k] = f2bf(Wout[k * 32 + n]);
        }
    } else {                              // WpoCatT bf16 [32n][64k]
        for (int x = tid; x < 2048; x += 256) {
            int n = x >> 6, k = x & 63;
            WpoCatT[n * 64 + k] = f2bf(Wpo[k * 32 + n]);
        }
    }
}

// ---------------------------------------------------------------------------
// kA: fused projection + chunk-local scan. Block = (b, chunk) = 256 tokens.
// Wave w owns tokens [w*64, (w+1)*64): 4 row-tiles of 16. A-frags loaded
// straight from e (fp32 -> bf16 in regs, no LDS). B-frags from global
// (L2-resident WuT). Scan: 2 channels/thread (b32 LDS ops), 8 sub-chunks.
// LDS: utile 32 KB + eSub 2 KB -> 4 blocks/CU.
__global__ __launch_bounds__(256) void kA_proj_scan(const float* __restrict__ e,
    const u16* __restrict__ WuT, const float* __restrict__ bu,
    const float* __restrict__ a_arr, const float* __restrict__ l2a,
    u16* __restrict__ h, float* __restrict__ Ebuf)
{
    __shared__ __align__(16) u16 utile[256 * 64];
    __shared__ float eSub[8][64];
    const int tid = threadIdx.x;
    const int blk = blockIdx.x;
    const size_t t0 = (size_t)blk * 256;
    const int lane = tid & 63, wave = tid >> 6;
    const int row16 = lane & 15, quad = lane >> 4;

    // ---- GEMM: u = e @ Wu + bu -> utile ----
    #pragma unroll 1
    for (int rt = 0; rt < 4; ++rt) {
        const int trow0 = wave * 64 + rt * 16;
        const float* erow = e + (t0 + trow0 + row16) * 256;
        f32x4 acc[4] = {{0.f,0.f,0.f,0.f},{0.f,0.f,0.f,0.f},{0.f,0.f,0.f,0.f},{0.f,0.f,0.f,0.f}};
        #pragma unroll
        for (int ks = 0; ks < 8; ++ks) {
            float4 a0 = *reinterpret_cast<const float4*>(erow + ks * 32 + quad * 8);
            float4 a1 = *reinterpret_cast<const float4*>(erow + ks * 32 + quad * 8 + 4);
            union { bf16x8 v; u16 s[8]; } af;
            af.s[0] = f2bf(a0.x); af.s[1] = f2bf(a0.y);
            af.s[2] = f2bf(a0.z); af.s[3] = f2bf(a0.w);
            af.s[4] = f2bf(a1.x); af.s[5] = f2bf(a1.y);
            af.s[6] = f2bf(a1.z); af.s[7] = f2bf(a1.w);
            #pragma unroll
            for (int ct = 0; ct < 4; ++ct) {
                bf16x8 bv = *reinterpret_cast<const bf16x8*>(WuT + (ct * 16 + row16) * 256 + ks * 32 + quad * 8);
                acc[ct] = MFMA16(af.v, bv, acc[ct]);
            }
        }
        #pragma unroll
        for (int ct = 0; ct < 4; ++ct) {     // C/D: col=lane&15, row=quad*4+r
            int col = ct * 16 + row16;
            float bias = bu[col];
            #pragma unroll
            for (int r = 0; r < 4; ++r) {
                int trow = trow0 + quad * 4 + r;
                utile[trow * 64 + col] = f2bf(acc[ct][r] + bias);
            }
        }
    }
    // NOTE: no barrier — scan sub-chunk (tid>>5)/2 == wave's own rows.

    // ---- chunk-local scan: 2 channels per thread, 8 sub-chunks of 32 ----
    const int c2 = tid & 31, sid = tid >> 5;          // sid>>1 == wave
    const int ch0 = c2 * 2, ch1 = ch0 + 1;
    const bool fwd = (ch0 < 32);
    const float a0 = a_arr[ch0], a1 = a_arr[ch1];
    u32* ut32 = reinterpret_cast<u32*>(utile);

    float h0 = 0.f, h1 = 0.f;
    if (fwd) {
        for (int i = 0; i < 32; ++i) {
            int t = sid * 32 + i;
            u32 w = ut32[t * 32 + c2];
            h0 = fmaf(a0, h0, bf2f((u16)(w & 0xFFFFu)));
            h1 = fmaf(a1, h1, bf2f((u16)(w >> 16)));
            ut32[t * 32 + c2] = (u32)f2bf(h0) | ((u32)f2bf(h1) << 16);
        }
    } else {
        for (int i = 31; i >= 0; --i) {
            int t = sid * 32 + i;
            u32 w = ut32[t * 32 + c2];
            h0 = fmaf(a0, h0, bf2f((u16)(w & 0xFFFFu)));
            h1 = fmaf(a1, h1, bf2f((u16)(w >> 16)));
            ut32[t * 32 + c2] = (u32)f2bf(h0) | ((u32)f2bf(h1) << 16);
        }
    }
    eSub[sid][ch0] = h0;
    eSub[sid][ch1] = h1;
    __syncthreads();

    const float A0 = exp2f(32.f * l2a[ch0]);          // a^32
    const float A1 = exp2f(32.f * l2a[ch1]);
    float cin0 = 0.f, cin1 = 0.f;
    if (fwd) {
        for (int j = 0; j < sid; ++j) {
            cin0 = fmaf(A0, cin0, eSub[j][ch0]);
            cin1 = fmaf(A1, cin1, eSub[j][ch1]);
        }
    } else {
        for (int j = 7; j > sid; --j) {
            cin0 = fmaf(A0, cin0, eSub[j][ch0]);
            cin1 = fmaf(A1, cin1, eSub[j][ch1]);
        }
    }
    if (fwd && sid == 7) {
        Ebuf[(size_t)blk * 64 + ch0] = fmaf(A0, cin0, eSub[7][ch0]);
        Ebuf[(size_t)blk * 64 + ch1] = fmaf(A1, cin1, eSub[7][ch1]);
    }
    if (!fwd && sid == 0) {
        Ebuf[(size_t)blk * 64 + ch0] = fmaf(A0, cin0, eSub[0][ch0]);
        Ebuf[(size_t)blk * 64 + ch1] = fmaf(A1, cin1, eSub[0][ch1]);
    }

    float p0 = cin0, p1 = cin1;
    if (fwd) {
        for (int i = 0; i < 32; ++i) {
            int t = sid * 32 + i;
            p0 *= a0; p1 *= a1;
            u32 w = ut32[t * 32 + c2];
            float v0 = bf2f((u16)(w & 0xFFFFu)) + p0;
            float v1 = bf2f((u16)(w >> 16)) + p1;
            ut32[t * 32 + c2] = (u32)f2bf(v0) | ((u32)f2bf(v1) << 16);
        }
    } else {
        for (int i = 31; i >= 0; --i) {
            int t = sid * 32 + i;
            p0 *= a0; p1 *= a1;
            u32 w = ut32[t * 32 + c2];
            float v0 = bf2f((u16)(w & 0xFFFFu)) + p0;
            float v1 = bf2f((u16)(w >> 16)) + p1;
            ut32[t * 32 + c2] = (u32)f2bf(v0) | ((u32)f2bf(v1) << 16);
        }
    }
    __syncthreads();
    uint4* gw = reinterpret_cast<uint4*>(h + t0 * 64);
    const uint4* s4 = reinterpret_cast<const uint4*>(utile);
    #pragma unroll
    for (int i = 0; i < 8; ++i) gw[tid + 256 * i] = s4[tid + 256 * i];
}

// ---------------------------------------------------------------------------
__global__ void k3_carry(const float* __restrict__ Ebuf, float* __restrict__ Cin,
                         const float* __restrict__ l2a)
{
    int tid = blockIdx.x * 256 + threadIdx.x;
    if (tid >= BB * NCH) return;
    int b = tid >> 6, ch = tid & 63;
    float aL = exp2f((float)LCH * l2a[ch]);      // a^256
    float S = 0.f;
    if (ch < 32) {
        for (int c = 0; c < NCHUNK; ++c) {
            size_t idx = ((size_t)(b * NCHUNK + c)) * 64 + ch;
            Cin[idx] = S; S = fmaf(aL, S, Ebuf[idx]);
        }
    } else {
        for (int c = NCHUNK - 1; c >= 0; --c) {
            size_t idx = ((size_t)(b * NCHUNK + c)) * 64 + ch;
            Cin[idx] = S; S = fmaf(aL, S, Ebuf[idx]);
        }
    }
}

// ---------------------------------------------------------------------------
// kB: all-MFMA epilogue. Block = (b, chunk) = 256 tokens; wave owns 64 rows.
// No __syncthreads: every LDS region is produced & consumed by the same wave.
// Carry-fixup decay powers via incremental a^16 recurrence (cin folded in).
__global__ __launch_bounds__(256) void kB_out(const u16* __restrict__ h,
    const float* __restrict__ Cin, const float* __restrict__ l2a,
    const float* __restrict__ a16p,
    const u16* __restrict__ WoutTbf, const float* __restrict__ fbout, const float* __restrict__ bbout,
    const u16* __restrict__ W1Tbf, const float* __restrict__ fb1, const float* __restrict__ bb1,
    const u16* __restrict__ WpoCatT, const u16* __restrict__ W2poCatT,
    const float* __restrict__ bc, float* __restrict__ out)
{
    __shared__ __align__(16) u16 Yt[256 * 64];       // [token][dir*32+n], swizzled
    __shared__ __align__(16) u16 Zw[4][16 * 128];    // per-wave scratch, swizzled
    const int tid = threadIdx.x;
    const int blk = blockIdx.x;
    const size_t t0 = (size_t)blk * 256;
    const int lane = tid & 63, wave = tid >> 6;
    const int row16 = lane & 15, quad = lane >> 4;
    const float* cinp = Cin + (size_t)blk * 64;      // uniform per block

    // ---- phase 1: Y = (h + cin*a^off) @ Wout + bout  -> Yt ----
    #pragma unroll
    for (int dir = 0; dir < 2; ++dir) {
        const float* boutp = dir ? bbout : fbout;
        float pw[8], A16[8];
        #pragma unroll
        for (int j = 0; j < 8; ++j) {
            const int chn = dir * 32 + quad * 8 + j;
            A16[j] = a16p[chn];
            // first off in iteration order: fwd rr=0 -> kpos+1; bwd rr=3 -> 256-kpos
            const float off0 = dir ? (float)(256 - wave * 64 - 48 - row16)
                                   : (float)(wave * 64 + row16 + 1);
            pw[j] = exp2f(off0 * l2a[chn]) * cinp[chn];
        }
        #pragma unroll 1
        for (int rri = 0; rri < 4; ++rri) {
            const int rr = dir ? (3 - rri) : rri;    // bwd iterates rr descending
            const int rt = wave * 4 + rr;
            const int kpos = rt * 16 + row16;
            uint4 hv = *reinterpret_cast<const uint4*>(h + (t0 + kpos) * 64 + dir * 32 + quad * 8);
            u32 hw[4] = {hv.x, hv.y, hv.z, hv.w};
            union { bf16x8 v; u16 s[8]; } af;
            #pragma unroll
            for (int j = 0; j < 8; ++j) {
                float f = bf2f((u16)((hw[j >> 1] >> ((j & 1) * 16)) & 0xFFFFu)) + pw[j];
                af.s[j] = f2bf(f);
                pw[j] *= A16[j];
            }
            f32x4 yv[2] = {{0.f,0.f,0.f,0.f},{0.f,0.f,0.f,0.f}};
            #pragma unroll
            for (int nt = 0; nt < 2; ++nt) {
                bf16x8 bv = *reinterpret_cast<const bf16x8*>(WoutTbf + dir * 1024 + (nt * 16 + row16) * 32 + quad * 8);
                yv[nt] = MFMA16(af.v, bv, yv[nt]);
            }
            #pragma unroll
            for (int nt = 0; nt < 2; ++nt) {
                float bb = boutp[nt * 16 + row16];
                #pragma unroll
                for (int r = 0; r < 4; ++r) {
                    int row = rt * 16 + quad * 4 + r;
                    int col = dir * 32 + nt * 16 + row16;
                    int cs = (col >> 3) ^ (row & 7);
                    Yt[row * 64 + cs * 8 + (col & 7)] = f2bf(yv[nt][r] + bb);
                }
            }
        }
    }

    // ---- phase 2: OUT = Ycat@Wpo + gelu(Y@W1+b1)@W2po + bc ----
    #pragma unroll 1
    for (int rr = 0; rr < 4; ++rr) {
        const int rt = wave * 4 + rr;
        const int arow = rt * 16 + row16;            // A row (token)
        f32x4 o0 = {0.f,0.f,0.f,0.f}, o1 = {0.f,0.f,0.f,0.f};

        // residual path: Ycat (K=64) @ WpoCat
        #pragma unroll
        for (int kb = 0; kb < 2; ++kb) {
            int cs = (kb * 4 + quad) ^ (arow & 7);
            bf16x8 av = *reinterpret_cast<const bf16x8*>(&Yt[arow * 64 + cs * 8]);
            bf16x8 bv0 = *reinterpret_cast<const bf16x8*>(WpoCatT + (row16) * 64 + kb * 32 + quad * 8);
            bf16x8 bv1 = *reinterpret_cast<const bf16x8*>(WpoCatT + (16 + row16) * 64 + kb * 32 + quad * 8);
            o0 = MFMA16(av, bv0, o0);
            o1 = MFMA16(av, bv1, o1);
        }
        // Z = gelu(Y_dir @ W1_dir + b1) -> Zw (per-wave, swizzled)
        #pragma unroll
        for (int dir = 0; dir < 2; ++dir) {
            int cs = (dir * 4 + quad) ^ (arow & 7);
            bf16x8 av = *reinterpret_cast<const bf16x8*>(&Yt[arow * 64 + cs * 8]);
            const float* b1p = dir ? bb1 : fb1;
            #pragma unroll
            for (int nt2 = 0; nt2 < 4; ++nt2) {
                f32x4 z = {0.f,0.f,0.f,0.f};
                bf16x8 bv = *reinterpret_cast<const bf16x8*>(W1Tbf + dir * 2048 + (nt2 * 16 + row16) * 32 + quad * 8);
                z = MFMA16(av, bv, z);
                float bb = b1p[nt2 * 16 + row16];
                #pragma unroll
                for (int r = 0; r < 4; ++r) {
                    float zz = gelu_tanh(z[r] + bb);
                    int zrow = quad * 4 + r;
                    int zcol = dir * 64 + nt2 * 16 + row16;
                    int zcs = (zcol >> 3) ^ (zrow & 7);
                    Zw[wave][zrow * 128 + zcs * 8 + (zcol & 7)] = f2bf(zz);
                }
            }
        }
        // MLP path: Zcat (K=128) @ W2poCat
        #pragma unroll
        for (int kb = 0; kb < 4; ++kb) {
            int zcs = (kb * 4 + quad) ^ (row16 & 7);
            bf16x8 av = *reinterpret_cast<const bf16x8*>(&Zw[wave][row16 * 128 + zcs * 8]);
            bf16x8 bv0 = *reinterpret_cast<const bf16x8*>(W2poCatT + (row16) * 128 + kb * 32 + quad * 8);
            bf16x8 bv1 = *reinterpret_cast<const bf16x8*>(W2poCatT + (16 + row16) * 128 + kb * 32 + quad * 8);
            o0 = MFMA16(av, bv0, o0);
            o1 = MFMA16(av, bv1, o1);
        }
        #pragma unroll
        for (int r = 0; r < 4; ++r) {
            size_t row = t0 + rt * 16 + quad * 4 + r;
            out[row * 32 + row16]      = o0[r] + bc[row16];
            out[row * 32 + 16 + row16] = o1[r] + bc[16 + row16];
        }
    }
}

// ---------------------------------------------------------------------------
extern "C" void kernel_launch(void* const* d_in, const int* in_sizes, int n_in,
                              void* d_out, int out_size, void* d_ws, size_t ws_size,
                              hipStream_t stream)
{
    (void)in_sizes; (void)n_in; (void)out_size; (void)ws_size;
    const float* e     = (const float*)d_in[0];
    const float* Wpi   = (const float*)d_in[1];
    const float* bpi   = (const float*)d_in[2];
    const float* Wpo   = (const float*)d_in[3];
    const float* bpo   = (const float*)d_in[4];
    const float* fWin  = (const float*)d_in[5];
    const float* fbin  = (const float*)d_in[6];
    const float* floga = (const float*)d_in[7];
    const float* fWout = (const float*)d_in[8];
    const float* fbout = (const float*)d_in[9];
    const float* fW1   = (const float*)d_in[10];
    const float* fb1   = (const float*)d_in[11];
    const float* fW2   = (const float*)d_in[12];
    const float* fb2   = (const float*)d_in[13];
    const float* bWin  = (const float*)d_in[14];
    const float* bbin  = (const float*)d_in[15];
    const float* bloga = (const float*)d_in[16];
    const float* bWout = (const float*)d_in[17];
    const float* bbout = (const float*)d_in[18];
    const float* bW1   = (const float*)d_in[19];
    const float* bb1   = (const float*)d_in[20];
    const float* bW2   = (const float*)d_in[21];
    const float* bb2   = (const float*)d_in[22];
    float* outp = (float*)d_out;

    char* ws = (char*)d_ws;
    size_t off = 0;
    auto walloc = [&](size_t bytes) { void* p = ws + off; off += (bytes + 255) & ~(size_t)255; return p; };
    u16*   hbuf  = (u16*)  walloc((size_t)BT * 64 * 2);       // 32 MB h_local
    u16*   WuT   = (u16*)  walloc(64 * 256 * 2);
    float* bu    = (float*)walloc(64 * 4);
    float* a_arr = (float*)walloc(64 * 4);
    float* l2a   = (float*)walloc(64 * 4);
    float* a16p  = (float*)walloc(64 * 4);
    float* Ebuf  = (float*)walloc((size_t)BB * NCHUNK * 64 * 4);
    float* Cin   = (float*)walloc((size_t)BB * NCHUNK * 64 * 4);
    u16*   W1Tbf    = (u16*)walloc(2 * 64 * 32 * 2);
    u16*   W2poCatT = (u16*)walloc(32 * 128 * 2);
    u16*   WoutTbf  = (u16*)walloc(2 * 32 * 32 * 2);
    u16*   WpoCatT  = (u16*)walloc(32 * 64 * 2);
    float* bc    = (float*)walloc(32 * 4);

    k0_prep<<<72, 256, 0, stream>>>(Wpi, bpi, fWin, fbin, floga, bWin, bbin, bloga,
                                    fW1, bW1, fW2, bW2, fb2, bb2, fWout, bWout, Wpo, bpo,
                                    WuT, bu, a_arr, l2a, a16p, W1Tbf, W2poCatT, WoutTbf, WpoCatT, bc);
    kA_proj_scan<<<BB * NCHUNK, 256, 0, stream>>>(e, WuT, bu, a_arr, l2a, hbuf, Ebuf);
    k3_carry<<<8, 256, 0, stream>>>(Ebuf, Cin, l2a);
    kB_out<<<BB * NCHUNK, 256, 0, stream>>>(hbuf, Cin, l2a, a16p,
                                            WoutTbf, fbout, bbout,
                                            W1Tbf, fb1, bb1,
                                            WpoCatT, W2poCatT, bc, outp);
}